// Round 29
// baseline (193.869 us; speedup 1.0000x reference)
//
#include <hip/hip_runtime.h>
#include <hip/hip_bf16.h>
#include <math.h>

#define NN 50000
#define EE 500000
#define ETOT (EE + NN)
#define NG 64

typedef __attribute__((ext_vector_type(8))) short short8v;   // 8 bf16 (4 VGPRs)
typedef __attribute__((ext_vector_type(4))) float float4v;   // 4 fp32 acc
typedef __attribute__((ext_vector_type(2))) float float2v;

__device__ __forceinline__ float bf2f(unsigned short u) {
    unsigned int v = ((unsigned int)u) << 16;
    return __builtin_bit_cast(float, v);
}
__device__ __forceinline__ unsigned short f2bf(float f) {
    __hip_bfloat16 h = __float2bfloat16(f);
    return *(unsigned short*)&h;
}

// ---------------- prep: zero scratch || W1->bf16 || x->bf16 ---------------
__global__ void k_prep(uint4* __restrict__ zp, int n16, int zB,
                       const float* __restrict__ W1, unsigned short* __restrict__ wb,
                       const float* __restrict__ x, unsigned short* __restrict__ xb) {
    int b = blockIdx.x;
    if (b < zB) {
        int t = b * 256 + threadIdx.x;
        if (t < n16) zp[t] = make_uint4(0, 0, 0, 0);
    } else if (b < zB + 128) {
        int t = (b - zB) * 256 + threadIdx.x;     // 32768 = 128*256 exactly
        wb[t] = f2bf(W1[t]);
    } else {
        int t = (b - zB - 128) * 256 + threadIdx.x;
        if (t < NN * 128 / 8) {
            float4 a = *(const float4*)&x[(size_t)t * 8];
            float4 c = *(const float4*)&x[(size_t)t * 8 + 4];
            float f[8] = {a.x, a.y, a.z, a.w, c.x, c.y, c.z, c.w};
            short8v vh;
#pragma unroll
            for (int j = 0; j < 8; ++j) vh[j] = (short)f2bf(f[j]);
            *(short8v*)&xb[(size_t)t * 8] = vh;
        }
    }
}

// ---------------- big: hist (4 edges/thread ILP) || GEMM1, interleaved ----
// Each hist thread issues 4 INDEPENDENT atomics back-to-back (pipelined
// latency); hist block count drops 2149 -> 538 freeing slots for gemm.
__global__ __launch_bounds__(256) void k_big(int gemmB, int gEh,
                                             const int* __restrict__ ei,
                                             const int* __restrict__ batch,
                                             int* __restrict__ counts,
                                             int* __restrict__ ord,
                                             int* __restrict__ gcount,
                                             const unsigned short* __restrict__ xb,
                                             const unsigned short* __restrict__ wb,
                                             const float* __restrict__ att_s,
                                             const float* __restrict__ att_d,
                                             unsigned char* __restrict__ h1f8,
                                             float* __restrict__ alpha_s,
                                             float* __restrict__ alpha_d) {
    int bx = (int)blockIdx.x;
    bool isHist;
    int idx;
    if (bx < 2 * gEh) {
        isHist = !(bx & 1);
        idx = bx >> 1;
    } else {
        isHist = false;
        idx = bx - gEh;
    }
    if (isHist) {
        int t0 = idx * 1024 + threadIdx.x * 4;
        if (t0 < ETOT) {
            int d0, d1, d2, d3;
            if (t0 + 3 < EE) {
                int4 dv = *(const int4*)&ei[EE + t0];
                d0 = dv.x; d1 = dv.y; d2 = dv.z; d3 = dv.w;
            } else {
                d0 = (t0 < EE) ? ei[EE + t0] : (t0 - EE);
                d1 = (t0 + 1 < EE) ? ei[EE + t0 + 1] : (t0 + 1 - EE);
                d2 = (t0 + 2 < EE) ? ei[EE + t0 + 2] : (t0 + 2 - EE);
                d3 = (t0 + 3 < EE) ? ei[EE + t0 + 3] : (t0 + 3 - EE);
            }
            // independent atomics -> pipelined
            if (t0 < ETOT)     ord[t0]     = atomicAdd(counts + d0, 1);
            if (t0 + 1 < ETOT) ord[t0 + 1] = atomicAdd(counts + d1, 1);
            if (t0 + 2 < ETOT) ord[t0 + 2] = atomicAdd(counts + d2, 1);
            if (t0 + 3 < ETOT) ord[t0 + 3] = atomicAdd(counts + d3, 1);
        }
        // per-graph node counts (batch sorted; ballot-aggregate per j)
#pragma unroll
        for (int j = 0; j < 4; ++j) {
            int t = t0 + j;
            if (t < NN) {
                int g = batch[t];
                int g0 = __shfl(g, 0);
                bool same = (g == g0);
                unsigned long long m = __ballot(same);
                if (same) {
                    if ((threadIdx.x & 63) == (__ffsll((long long)m) - 1))
                        atomicAdd(gcount + g0, (int)__popcll(m));
                } else {
                    atomicAdd(gcount + g, 1);
                }
            }
        }
        return;
    }
    // ---- GEMM1 via bf16 MFMA + fused alpha logits ----
    int w = threadIdx.x >> 6;
    int l = threadIdx.x & 63;
    int bm0 = idx * 32;
    int i16 = l & 15;
    int kb = (l >> 4) * 8;
    int colb = w * 64;

    short8v a[2][4];
#pragma unroll
    for (int mi = 0; mi < 2; ++mi) {
        int r = bm0 + mi * 16 + i16;
#pragma unroll
        for (int k = 0; k < 4; ++k) {
            if (r < NN) a[mi][k] = *(const short8v*)&xb[(size_t)r * 128 + k * 32 + kb];
            else        a[mi][k] = (short8v){0,0,0,0,0,0,0,0};
        }
    }

    float4v acc[2][4];
#pragma unroll
    for (int mi = 0; mi < 2; ++mi)
#pragma unroll
        for (int ni = 0; ni < 4; ++ni)
            acc[mi][ni] = (float4v){0.f, 0.f, 0.f, 0.f};

#pragma unroll
    for (int k = 0; k < 4; ++k) {
#pragma unroll
        for (int ni = 0; ni < 4; ++ni) {
            short8v b = *(const short8v*)&wb[(size_t)(colb + ni * 16 + i16) * 128 + k * 32 + kb];
            acc[0][ni] = __builtin_amdgcn_mfma_f32_16x16x32_bf16(a[0][k], b, acc[0][ni], 0, 0, 0);
            acc[1][ni] = __builtin_amdgcn_mfma_f32_16x16x32_bf16(a[1][k], b, acc[1][ni], 0, 0, 0);
        }
    }

    int drb = (l >> 4) * 4;
    int dc = l & 15;
    float asw[4], adw[4];
#pragma unroll
    for (int ni = 0; ni < 4; ++ni) {
        asw[ni] = att_s[colb + ni * 16 + dc];
        adw[ni] = att_d[colb + ni * 16 + dc];
    }
#pragma unroll
    for (int mi = 0; mi < 2; ++mi) {
#pragma unroll
        for (int r = 0; r < 4; ++r) {
            int row = bm0 + mi * 16 + drb + r;
            float v0 = acc[mi][0][r], v1 = acc[mi][1][r];
            float v2 = acc[mi][2][r], v3 = acc[mi][3][r];
            float s = v0 * asw[0] + v1 * asw[1] + v2 * asw[2] + v3 * asw[3];
            float d = v0 * adw[0] + v1 * adw[1] + v2 * adw[2] + v3 * adw[3];
            unsigned int packed = __builtin_amdgcn_cvt_pk_fp8_f32(v0, v1, 0u, false);
            packed = __builtin_amdgcn_cvt_pk_fp8_f32(v2, v3, packed, true);
            if (row < NN)
                *(unsigned int*)&h1f8[((unsigned)row << 8) + (unsigned)(colb + (dc << 2))] = packed;
#pragma unroll
            for (int m = 8; m >= 1; m >>= 1) {
                s += __shfl_xor(s, m);
                d += __shfl_xor(d, m);
            }
            if (dc == 0 && row < NN) {
                alpha_s[row * 4 + w] = s;
                alpha_d[row * 4 + w] = d;
            }
        }
    }
}

// ---------------- exclusive scan counts -> indptr (1024 threads) ----------
__global__ void k_scan(const int* __restrict__ counts, int* __restrict__ indptr) {
    __shared__ int wsum[16];
    __shared__ int carry_s;
    int tid = threadIdx.x;
    int lane = tid & 63;
    int w = tid >> 6;
    int4 v[13];
#pragma unroll
    for (int c = 0; c < 13; ++c) {
        int i = c * 4096 + tid * 4;
        if (i + 3 < NN) {
            v[c] = *(const int4*)&counts[i];
        } else {
            v[c] = make_int4(0, 0, 0, 0);
            if (i < NN) v[c].x = counts[i];
            if (i + 1 < NN) v[c].y = counts[i + 1];
            if (i + 2 < NN) v[c].z = counts[i + 2];
        }
    }
    if (tid == 0) carry_s = 0;
    __syncthreads();
#pragma unroll
    for (int c = 0; c < 13; ++c) {
        int i = c * 4096 + tid * 4;
        int v0 = v[c].x, v1 = v[c].y, v2 = v[c].z, v3 = v[c].w;
        int tot = v0 + v1 + v2 + v3;
        int s = tot;
#pragma unroll
        for (int off = 1; off < 64; off <<= 1) {
            int u = __shfl_up(s, off);
            if (lane >= off) s += u;
        }
        if (lane == 63) wsum[w] = s;
        __syncthreads();
        if (w == 0) {
            int t2 = (lane < 16) ? wsum[lane] : 0;
#pragma unroll
            for (int off = 1; off < 16; off <<= 1) {
                int u = __shfl_up(t2, off);
                if (lane >= off) t2 += u;
            }
            if (lane < 16) wsum[lane] = t2;
        }
        __syncthreads();
        int wpre = (w == 0) ? 0 : wsum[w - 1];
        int incl = s + wpre;
        int carry = carry_s;
        int e = carry + incl - tot;
        if (i < NN)     indptr[i] = e;
        if (i + 1 < NN) indptr[i + 1] = e + v0;
        if (i + 2 < NN) indptr[i + 2] = e + v0 + v1;
        if (i + 3 < NN) indptr[i + 3] = e + v0 + v1 + v2;
        __syncthreads();
        if (tid == 1023) carry_s = carry + incl;
        __syncthreads();
    }
    if (tid == 0) indptr[NN] = carry_s;
}

// ---------------- bucket fill (no atomic): p = indptr[dst] + ord[t] -------
__global__ void k_fill(const int* __restrict__ ei, const int* __restrict__ indptr,
                       const int* __restrict__ ord,
                       const float* __restrict__ als, const float* __restrict__ ald,
                       uint4* __restrict__ edges, int* __restrict__ srcs) {
    int t = blockIdx.x * 256 + threadIdx.x;
    if (t >= ETOT) return;
    int src = (t < EE) ? ei[t] : (t - EE);
    int dst = (t < EE) ? ei[EE + t] : (t - EE);
    int p = indptr[dst] + ord[t];
    float4 as = *(const float4*)&als[src * 4];
    float4 ad = *(const float4*)&ald[dst * 4];
    float e0 = as.x + ad.x, e1 = as.y + ad.y, e2 = as.z + ad.z, e3 = as.w + ad.w;
    e0 = e0 > 0.f ? e0 : 0.2f * e0;
    e1 = e1 > 0.f ? e1 : 0.2f * e1;
    e2 = e2 > 0.f ? e2 : 0.2f * e2;
    e3 = e3 > 0.f ? e3 : 0.2f * e3;
    unsigned int ee01 = (unsigned int)f2bf(__expf(e0)) | ((unsigned int)f2bf(__expf(e1)) << 16);
    unsigned int ee23 = (unsigned int)f2bf(__expf(e2)) | ((unsigned int)f2bf(__expf(e3)) << 16);
    edges[p] = make_uint4((unsigned int)src, ee01, ee23, (unsigned int)dst);
    srcs[p] = src;
}

// ---------------- gather1 + softmax + bias + ELU + fused GEMM2 ------------
__global__ void k_gather1(const int* __restrict__ indptr, const uint4* __restrict__ edges,
                          const unsigned char* __restrict__ h1f8, const float* __restrict__ b1,
                          const float* __restrict__ W2, const float* __restrict__ as2v,
                          const float* __restrict__ ad2v, float* __restrict__ h2lin,
                          float* __restrict__ als2, float* __restrict__ ald2) {
    int wid = (blockIdx.x * 256 + threadIdx.x) >> 6;
    int l = threadIdx.x & 63;
    if (wid >= NN) return;
    int p0 = __builtin_amdgcn_readfirstlane(indptr[wid]);
    int p1 = __builtin_amdgcn_readfirstlane(indptr[wid + 1]);
    int last = p1 - 1;
    int head = l >> 4;
    unsigned sel = (head == 0) ? 0x01000C0Cu : (head == 1) ? 0x03020C0Cu
                 : (head == 2) ? 0x05040C0Cu : 0x07060C0Cu;
    unsigned lofs = (unsigned)(l << 2);
    float2v accA = {0.f, 0.f}, accB = {0.f, 0.f};
    float dsum = 0.f;
    for (int p = p0; p < p1; p += 8) {
        uint4 e[8];
#pragma unroll
        for (int j = 0; j < 8; ++j) {
            int idx = p + j;
            e[j] = edges[idx < p1 ? idx : last];
        }
        unsigned int hv[8];
#pragma unroll
        for (int j = 0; j < 8; ++j)
            hv[j] = *(const unsigned int*)(h1f8 + (((unsigned)e[j].x << 8) | lofs));
#pragma unroll
        for (int j = 0; j < 8; ++j) {
#if __has_builtin(__builtin_amdgcn_perm)
            unsigned wu = __builtin_amdgcn_perm(e[j].z, e[j].y, sel);
#else
            unsigned packed = (head & 2) ? e[j].z : e[j].y;
            unsigned wu = (head & 1) ? (packed & 0xffff0000u) : (packed << 16);
#endif
            float wgt = __builtin_bit_cast(float, wu);
            wgt = (p + j < p1) ? wgt : 0.f;
            float2v lo = __builtin_amdgcn_cvt_pk_f32_fp8(hv[j], false);
            float2v hi = __builtin_amdgcn_cvt_pk_f32_fp8(hv[j], true);
            float2v w2 = {wgt, wgt};
            accA += w2 * lo;
            accB += w2 * hi;
            dsum += wgt;
        }
    }
    float inv = 1.0f / dsum;
    int cbase = head * 64 + (l & 15);
    float o0 = accA[0] * inv + b1[cbase];
    float o1 = accA[1] * inv + b1[cbase + 16];
    float o2 = accB[0] * inv + b1[cbase + 32];
    float o3 = accB[1] * inv + b1[cbase + 48];
    o0 = o0 > 0.f ? o0 : (__expf(o0) - 1.0f);
    o1 = o1 > 0.f ? o1 : (__expf(o1) - 1.0f);
    o2 = o2 > 0.f ? o2 : (__expf(o2) - 1.0f);
    o3 = o3 > 0.f ? o3 : (__expf(o3) - 1.0f);
    float t[10];
#pragma unroll
    for (int o = 0; o < 10; ++o) {
        const float* wr = &W2[o * 256 + cbase];
        t[o] = o0 * wr[0] + o1 * wr[16] + o2 * wr[32] + o3 * wr[48];
    }
#pragma unroll
    for (int m = 32; m > 0; m >>= 1) {
#pragma unroll
        for (int o = 0; o < 10; ++o) t[o] += __shfl_xor(t[o], m);
    }
    if (l == 0) {
        float as = 0.f, ad = 0.f;
#pragma unroll
        for (int o = 0; o < 10; ++o) {
            h2lin[(size_t)wid * 16 + o] = t[o];
            as += t[o] * as2v[o];
            ad += t[o] * ad2v[o];
        }
        als2[wid] = as;
        ald2[wid] = ad;
    }
}

// ---------------- gather layer 2 (predicated 4-wide, srcs-only) + pool ----
__global__ void k_g2pool(const int* __restrict__ indptr, const int* __restrict__ srcs,
                         const float* __restrict__ als2, const float* __restrict__ ald2,
                         const float* __restrict__ h2lin, const float* __restrict__ b2,
                         const int* __restrict__ batch, float* __restrict__ pooled) {
    int wave = (blockIdx.x * 256 + threadIdx.x) >> 6;
    int lane = threadIdx.x & 63;
    int grp = lane >> 4, c = lane & 15;
    int node = wave * 4 + grp;
    float acc = 0.f;
    int g = -1;
    if (node < NN) {
        int p0 = indptr[node], p1 = indptr[node + 1];
        int last = p1 - 1;
        float ad2n = ald2[node];
        float dsum = 0.f;
        for (int p = p0; p < p1; p += 4) {
            int i1 = p + 1, i2 = p + 2, i3 = p + 3;
            unsigned s0 = (unsigned)srcs[p];
            unsigned s1 = (unsigned)srcs[i1 < p1 ? i1 : last];
            unsigned s2 = (unsigned)srcs[i2 < p1 ? i2 : last];
            unsigned s3 = (unsigned)srcs[i3 < p1 ? i3 : last];
            float v0 = als2[s0] + ad2n;
            float v1 = als2[s1] + ad2n;
            float v2 = als2[s2] + ad2n;
            float v3 = als2[s3] + ad2n;
            float h0 = 0.f, h1_ = 0.f, h2 = 0.f, h3 = 0.f;
            if (c < 10) {
                h0 = h2lin[(s0 << 4) + (unsigned)c];
                h1_ = h2lin[(s1 << 4) + (unsigned)c];
                h2 = h2lin[(s2 << 4) + (unsigned)c];
                h3 = h2lin[(s3 << 4) + (unsigned)c];
            }
            v0 = v0 > 0.f ? v0 : 0.2f * v0;
            v1 = v1 > 0.f ? v1 : 0.2f * v1;
            v2 = v2 > 0.f ? v2 : 0.2f * v2;
            v3 = v3 > 0.f ? v3 : 0.2f * v3;
            float w0 = __expf(v0);
            float w1 = (i1 < p1) ? __expf(v1) : 0.f;
            float w2 = (i2 < p1) ? __expf(v2) : 0.f;
            float w3 = (i3 < p1) ? __expf(v3) : 0.f;
            dsum += (w0 + w1) + (w2 + w3);
            acc += w0 * h0 + w1 * h1_ + w2 * h2 + w3 * h3;
        }
        if (c < 10) acc = acc / dsum + b2[c];
        else acc = 0.f;
        g = batch[node];
    }
    int g0 = __shfl(g, 0);
    bool uni = __all((node >= NN) || (g == g0));
    if (uni) {
        if (g0 >= 0) {
            acc += __shfl_xor(acc, 16);
            acc += __shfl_xor(acc, 32);
            if (grp == 0 && c < 10)
                atomicAdd(pooled + g0 * 10 + c, acc);
        }
    } else if (node < NN && c < 10) {
        atomicAdd(pooled + g * 10 + c, acc);
    }
}

// ---------------- mean + log_softmax --------------------------------------
__global__ void k_final(const float* __restrict__ pooled, const int* __restrict__ gcount,
                        float* __restrict__ out) {
    int g = threadIdx.x;
    if (g >= NG) return;
    float c = fmaxf((float)gcount[g], 1.0f);
    float m[10];
    float mx = -1e30f;
#pragma unroll
    for (int i = 0; i < 10; ++i) {
        m[i] = pooled[g * 10 + i] / c;
        mx = fmaxf(mx, m[i]);
    }
    float s = 0.f;
#pragma unroll
    for (int i = 0; i < 10; ++i) s += expf(m[i] - mx);
    float lse = mx + logf(s);
#pragma unroll
    for (int i = 0; i < 10; ++i) out[g * 10 + i] = m[i] - lse;
}

extern "C" void kernel_launch(void* const* d_in, const int* in_sizes, int n_in,
                              void* d_out, int out_size, void* d_ws, size_t ws_size,
                              hipStream_t stream) {
    const float* x   = (const float*)d_in[0];
    const int*   ei  = (const int*)d_in[1];
    const int*   bat = (const int*)d_in[3];
    const float* W1  = (const float*)d_in[4];
    const float* as1 = (const float*)d_in[5];
    const float* ad1 = (const float*)d_in[6];
    const float* b1  = (const float*)d_in[7];
    const float* W2  = (const float*)d_in[8];
    const float* as2 = (const float*)d_in[9];
    const float* ad2 = (const float*)d_in[10];
    const float* b2  = (const float*)d_in[11];
    float* out = (float*)d_out;

    char* ws = (char*)d_ws;
    size_t off = 0;
    auto alloc = [&](size_t bytes) -> size_t {
        size_t o = off;
        off = (off + bytes + 255) & ~(size_t)255;
        return o;
    };
    size_t o_counts = alloc((size_t)NN * 4);
    size_t o_pooled = alloc((size_t)NG * 10 * 4);
    size_t o_gcount = alloc((size_t)NG * 4);
    size_t zero_bytes = off;
    size_t o_ord    = alloc((size_t)ETOT * 4);
    size_t o_indptr = alloc((size_t)(NN + 1) * 4);
    size_t o_edges  = alloc((size_t)ETOT * 16);
    size_t o_srcs   = alloc((size_t)ETOT * 4);
    size_t o_h1f8   = alloc((size_t)NN * 256);
    size_t o_als1   = alloc((size_t)NN * 4 * 4);
    size_t o_ald1   = alloc((size_t)NN * 4 * 4);
    size_t o_h2lin  = alloc((size_t)NN * 16 * 4);
    size_t o_als2   = alloc((size_t)NN * 4);
    size_t o_ald2   = alloc((size_t)NN * 4);
    size_t o_wb     = alloc((size_t)256 * 128 * 2);
    size_t o_xb     = alloc((size_t)NN * 128 * 2);
    (void)ws_size;

    int*   counts = (int*)(ws + o_counts);
    float* pooled = (float*)(ws + o_pooled);
    int*   gcount = (int*)(ws + o_gcount);
    int*   ord    = (int*)(ws + o_ord);
    int*   indptr = (int*)(ws + o_indptr);
    uint4* edges  = (uint4*)(ws + o_edges);
    int*   srcs   = (int*)(ws + o_srcs);
    unsigned char*  h1f8 = (unsigned char*)(ws + o_h1f8);
    float* als1   = (float*)(ws + o_als1);
    float* ald1   = (float*)(ws + o_ald1);
    float* h2lin  = (float*)(ws + o_h2lin);
    float* als2   = (float*)(ws + o_als2);
    float* ald2   = (float*)(ws + o_ald2);
    unsigned short* wb = (unsigned short*)(ws + o_wb);
    unsigned short* xb = (unsigned short*)(ws + o_xb);

    int n16 = (int)(zero_bytes / 16);
    int zB = (n16 + 255) / 256;
    int xB = (NN * 128 / 8 + 255) / 256;   // 3125
    int gE = (ETOT + 255) / 256;           // 2149
    int gEh = (ETOT + 1023) / 1024;        // 538 (4 edges/thread)
    int gW = (NN + 3) / 4;                 // 12500
    int gemmB = (NN + 31) / 32;            // 1563

    k_prep<<<zB + 128 + xB, 256, 0, stream>>>((uint4*)ws, n16, zB, W1, wb, x, xb);
    k_big<<<gEh + gemmB, 256, 0, stream>>>(gemmB, gEh, ei, bat, counts, ord, gcount,
                                           xb, wb, as1, ad1, h1f8, als1, ald1);
    k_scan<<<1, 1024, 0, stream>>>(counts, indptr);
    k_fill<<<gE, 256, 0, stream>>>(ei, indptr, ord, als1, ald1, edges, srcs);
    k_gather1<<<gW, 256, 0, stream>>>(indptr, edges, h1f8, b1, W2, as2, ad2,
                                      h2lin, als2, ald2);
    k_g2pool<<<gW, 256, 0, stream>>>(indptr, srcs, als2, ald2, h2lin, b2, bat, pooled);
    k_final<<<1, 64, 0, stream>>>(pooled, gcount, out);
    (void)n_in; (void)in_sizes; (void)out_size;
}

// Round 30
// 163.510 us; speedup vs baseline: 1.1857x; 1.1857x over previous
//
#include <hip/hip_runtime.h>
#include <hip/hip_bf16.h>
#include <math.h>

#define NN 50000
#define EE 500000
#define ETOT (EE + NN)
#define NG 64

typedef __attribute__((ext_vector_type(8))) short short8v;   // 8 bf16 (4 VGPRs)
typedef __attribute__((ext_vector_type(4))) float float4v;   // 4 fp32 acc
typedef __attribute__((ext_vector_type(2))) float float2v;

__device__ __forceinline__ float bf2f(unsigned short u) {
    unsigned int v = ((unsigned int)u) << 16;
    return __builtin_bit_cast(float, v);
}
__device__ __forceinline__ unsigned short f2bf(float f) {
    __hip_bfloat16 h = __float2bfloat16(f);
    return *(unsigned short*)&h;
}

// ---------------- prep: zero scratch || W1->bf16 || x->bf16 ---------------
__global__ void k_prep(uint4* __restrict__ zp, int n16, int zB,
                       const float* __restrict__ W1, unsigned short* __restrict__ wb,
                       const float* __restrict__ x, unsigned short* __restrict__ xb) {
    int b = blockIdx.x;
    if (b < zB) {
        int t = b * 256 + threadIdx.x;
        if (t < n16) zp[t] = make_uint4(0, 0, 0, 0);
    } else if (b < zB + 128) {
        int t = (b - zB) * 256 + threadIdx.x;     // 32768 = 128*256 exactly
        wb[t] = f2bf(W1[t]);
    } else {
        int t = (b - zB - 128) * 256 + threadIdx.x;
        if (t < NN * 128 / 8) {
            float4 a = *(const float4*)&x[(size_t)t * 8];
            float4 c = *(const float4*)&x[(size_t)t * 8 + 4];
            float f[8] = {a.x, a.y, a.z, a.w, c.x, c.y, c.z, c.w};
            short8v vh;
#pragma unroll
            for (int j = 0; j < 8; ++j) vh[j] = (short)f2bf(f[j]);
            *(short8v*)&xb[(size_t)t * 8] = vh;
        }
    }
}

// ---------------- big: hist || GEMM1, INTERLEAVED block mapping -----------
// Even blocks -> hist, odd -> gemm (while both remain); ensures both
// populations are co-resident so MFMA fills cycles under atomic latency.
__global__ __launch_bounds__(256) void k_big(int gemmB, int gE,
                                             const int* __restrict__ ei,
                                             const int* __restrict__ batch,
                                             int* __restrict__ counts,
                                             int* __restrict__ ord,
                                             int* __restrict__ gcount,
                                             const unsigned short* __restrict__ xb,
                                             const unsigned short* __restrict__ wb,
                                             const float* __restrict__ att_s,
                                             const float* __restrict__ att_d,
                                             unsigned char* __restrict__ h1f8,
                                             float* __restrict__ alpha_s,
                                             float* __restrict__ alpha_d) {
    int bx = (int)blockIdx.x;
    bool isHist;
    int idx;
    if (bx < 2 * gemmB) {
        isHist = !(bx & 1);
        idx = bx >> 1;
    } else {
        isHist = true;
        idx = bx - gemmB;
    }
    if (isHist) {
        // ---- histogram of dst + edge ordinal + graph counts ----
        int t = idx * 256 + threadIdx.x;
        if (t < ETOT) {
            int dst = (t < EE) ? ei[EE + t] : (t - EE);
            ord[t] = atomicAdd(counts + dst, 1);
        }
        if (t < NN) {
            int g = batch[t];
            int g0 = __shfl(g, 0);
            bool same = (g == g0);
            unsigned long long m = __ballot(same);
            if (same) {
                if ((threadIdx.x & 63) == (__ffsll((long long)m) - 1))
                    atomicAdd(gcount + g0, (int)__popcll(m));
            } else {
                atomicAdd(gcount + g, 1);
            }
        }
        return;
    }
    // ---- GEMM1 via bf16 MFMA + fused alpha logits ----
    // h1f8 layout (PERMUTED, must match gather1): byte = row*256+head*64+dc*4+ni
    int w = threadIdx.x >> 6;
    int l = threadIdx.x & 63;
    int bm0 = idx * 32;
    int i16 = l & 15;
    int kb = (l >> 4) * 8;
    int colb = w * 64;

    short8v a[2][4];
#pragma unroll
    for (int mi = 0; mi < 2; ++mi) {
        int r = bm0 + mi * 16 + i16;
#pragma unroll
        for (int k = 0; k < 4; ++k) {
            if (r < NN) a[mi][k] = *(const short8v*)&xb[(size_t)r * 128 + k * 32 + kb];
            else        a[mi][k] = (short8v){0,0,0,0,0,0,0,0};
        }
    }

    float4v acc[2][4];
#pragma unroll
    for (int mi = 0; mi < 2; ++mi)
#pragma unroll
        for (int ni = 0; ni < 4; ++ni)
            acc[mi][ni] = (float4v){0.f, 0.f, 0.f, 0.f};

#pragma unroll
    for (int k = 0; k < 4; ++k) {
#pragma unroll
        for (int ni = 0; ni < 4; ++ni) {
            short8v b = *(const short8v*)&wb[(size_t)(colb + ni * 16 + i16) * 128 + k * 32 + kb];
            acc[0][ni] = __builtin_amdgcn_mfma_f32_16x16x32_bf16(a[0][k], b, acc[0][ni], 0, 0, 0);
            acc[1][ni] = __builtin_amdgcn_mfma_f32_16x16x32_bf16(a[1][k], b, acc[1][ni], 0, 0, 0);
        }
    }

    int drb = (l >> 4) * 4;
    int dc = l & 15;
    float asw[4], adw[4];
#pragma unroll
    for (int ni = 0; ni < 4; ++ni) {
        asw[ni] = att_s[colb + ni * 16 + dc];
        adw[ni] = att_d[colb + ni * 16 + dc];
    }
#pragma unroll
    for (int mi = 0; mi < 2; ++mi) {
#pragma unroll
        for (int r = 0; r < 4; ++r) {
            int row = bm0 + mi * 16 + drb + r;
            float v0 = acc[mi][0][r], v1 = acc[mi][1][r];
            float v2 = acc[mi][2][r], v3 = acc[mi][3][r];
            float s = v0 * asw[0] + v1 * asw[1] + v2 * asw[2] + v3 * asw[3];
            float d = v0 * adw[0] + v1 * adw[1] + v2 * adw[2] + v3 * adw[3];
            unsigned int packed = __builtin_amdgcn_cvt_pk_fp8_f32(v0, v1, 0u, false);
            packed = __builtin_amdgcn_cvt_pk_fp8_f32(v2, v3, packed, true);
            if (row < NN)
                *(unsigned int*)&h1f8[((unsigned)row << 8) + (unsigned)(colb + (dc << 2))] = packed;
#pragma unroll
            for (int m = 8; m >= 1; m >>= 1) {
                s += __shfl_xor(s, m);
                d += __shfl_xor(d, m);
            }
            if (dc == 0 && row < NN) {
                alpha_s[row * 4 + w] = s;
                alpha_d[row * 4 + w] = d;
            }
        }
    }
}

// ---------------- exclusive scan counts -> indptr (1024 threads) ----------
__global__ void k_scan(const int* __restrict__ counts, int* __restrict__ indptr) {
    __shared__ int wsum[16];
    __shared__ int carry_s;
    int tid = threadIdx.x;
    int lane = tid & 63;
    int w = tid >> 6;
    int4 v[13];
#pragma unroll
    for (int c = 0; c < 13; ++c) {
        int i = c * 4096 + tid * 4;
        if (i + 3 < NN) {
            v[c] = *(const int4*)&counts[i];
        } else {
            v[c] = make_int4(0, 0, 0, 0);
            if (i < NN) v[c].x = counts[i];
            if (i + 1 < NN) v[c].y = counts[i + 1];
            if (i + 2 < NN) v[c].z = counts[i + 2];
        }
    }
    if (tid == 0) carry_s = 0;
    __syncthreads();
#pragma unroll
    for (int c = 0; c < 13; ++c) {
        int i = c * 4096 + tid * 4;
        int v0 = v[c].x, v1 = v[c].y, v2 = v[c].z, v3 = v[c].w;
        int tot = v0 + v1 + v2 + v3;
        int s = tot;
#pragma unroll
        for (int off = 1; off < 64; off <<= 1) {
            int u = __shfl_up(s, off);
            if (lane >= off) s += u;
        }
        if (lane == 63) wsum[w] = s;
        __syncthreads();
        if (w == 0) {
            int t2 = (lane < 16) ? wsum[lane] : 0;
#pragma unroll
            for (int off = 1; off < 16; off <<= 1) {
                int u = __shfl_up(t2, off);
                if (lane >= off) t2 += u;
            }
            if (lane < 16) wsum[lane] = t2;
        }
        __syncthreads();
        int wpre = (w == 0) ? 0 : wsum[w - 1];
        int incl = s + wpre;
        int carry = carry_s;
        int e = carry + incl - tot;
        if (i < NN)     indptr[i] = e;
        if (i + 1 < NN) indptr[i + 1] = e + v0;
        if (i + 2 < NN) indptr[i + 2] = e + v0 + v1;
        if (i + 3 < NN) indptr[i + 3] = e + v0 + v1 + v2;
        __syncthreads();
        if (tid == 1023) carry_s = carry + incl;
        __syncthreads();
    }
    if (tid == 0) indptr[NN] = carry_s;
}

// ---------------- bucket fill (no atomic): p = indptr[dst] + ord[t] -------
__global__ void k_fill(const int* __restrict__ ei, const int* __restrict__ indptr,
                       const int* __restrict__ ord,
                       const float* __restrict__ als, const float* __restrict__ ald,
                       uint4* __restrict__ edges, int* __restrict__ srcs) {
    int t = blockIdx.x * 256 + threadIdx.x;
    if (t >= ETOT) return;
    int src = (t < EE) ? ei[t] : (t - EE);
    int dst = (t < EE) ? ei[EE + t] : (t - EE);
    int p = indptr[dst] + ord[t];
    float4 as = *(const float4*)&als[src * 4];
    float4 ad = *(const float4*)&ald[dst * 4];
    float e0 = as.x + ad.x, e1 = as.y + ad.y, e2 = as.z + ad.z, e3 = as.w + ad.w;
    e0 = e0 > 0.f ? e0 : 0.2f * e0;
    e1 = e1 > 0.f ? e1 : 0.2f * e1;
    e2 = e2 > 0.f ? e2 : 0.2f * e2;
    e3 = e3 > 0.f ? e3 : 0.2f * e3;
    unsigned int ee01 = (unsigned int)f2bf(__expf(e0)) | ((unsigned int)f2bf(__expf(e1)) << 16);
    unsigned int ee23 = (unsigned int)f2bf(__expf(e2)) | ((unsigned int)f2bf(__expf(e3)) << 16);
    edges[p] = make_uint4((unsigned int)src, ee01, ee23, (unsigned int)dst);
    srcs[p] = src;
}

// ---------------- gather1 + softmax + bias + ELU + fused GEMM2 ------------
__global__ void k_gather1(const int* __restrict__ indptr, const uint4* __restrict__ edges,
                          const unsigned char* __restrict__ h1f8, const float* __restrict__ b1,
                          const float* __restrict__ W2, const float* __restrict__ as2v,
                          const float* __restrict__ ad2v, float* __restrict__ h2lin,
                          float* __restrict__ als2, float* __restrict__ ald2) {
    int wid = (blockIdx.x * 256 + threadIdx.x) >> 6;
    int l = threadIdx.x & 63;
    if (wid >= NN) return;
    int p0 = __builtin_amdgcn_readfirstlane(indptr[wid]);
    int p1 = __builtin_amdgcn_readfirstlane(indptr[wid + 1]);
    int last = p1 - 1;
    int head = l >> 4;
    unsigned sel = (head == 0) ? 0x01000C0Cu : (head == 1) ? 0x03020C0Cu
                 : (head == 2) ? 0x05040C0Cu : 0x07060C0Cu;
    unsigned lofs = (unsigned)(l << 2);
    float2v accA = {0.f, 0.f}, accB = {0.f, 0.f};
    float dsum = 0.f;
    for (int p = p0; p < p1; p += 8) {
        uint4 e[8];
#pragma unroll
        for (int j = 0; j < 8; ++j) {
            int idx = p + j;
            e[j] = edges[idx < p1 ? idx : last];
        }
        unsigned int hv[8];
#pragma unroll
        for (int j = 0; j < 8; ++j)
            hv[j] = *(const unsigned int*)(h1f8 + (((unsigned)e[j].x << 8) | lofs));
#pragma unroll
        for (int j = 0; j < 8; ++j) {
#if __has_builtin(__builtin_amdgcn_perm)
            unsigned wu = __builtin_amdgcn_perm(e[j].z, e[j].y, sel);
#else
            unsigned packed = (head & 2) ? e[j].z : e[j].y;
            unsigned wu = (head & 1) ? (packed & 0xffff0000u) : (packed << 16);
#endif
            float wgt = __builtin_bit_cast(float, wu);
            wgt = (p + j < p1) ? wgt : 0.f;
            float2v lo = __builtin_amdgcn_cvt_pk_f32_fp8(hv[j], false);
            float2v hi = __builtin_amdgcn_cvt_pk_f32_fp8(hv[j], true);
            float2v w2 = {wgt, wgt};
            accA += w2 * lo;
            accB += w2 * hi;
            dsum += wgt;
        }
    }
    float inv = 1.0f / dsum;
    int cbase = head * 64 + (l & 15);
    float o0 = accA[0] * inv + b1[cbase];
    float o1 = accA[1] * inv + b1[cbase + 16];
    float o2 = accB[0] * inv + b1[cbase + 32];
    float o3 = accB[1] * inv + b1[cbase + 48];
    o0 = o0 > 0.f ? o0 : (__expf(o0) - 1.0f);
    o1 = o1 > 0.f ? o1 : (__expf(o1) - 1.0f);
    o2 = o2 > 0.f ? o2 : (__expf(o2) - 1.0f);
    o3 = o3 > 0.f ? o3 : (__expf(o3) - 1.0f);
    float t[10];
#pragma unroll
    for (int o = 0; o < 10; ++o) {
        const float* wr = &W2[o * 256 + cbase];
        t[o] = o0 * wr[0] + o1 * wr[16] + o2 * wr[32] + o3 * wr[48];
    }
#pragma unroll
    for (int m = 32; m > 0; m >>= 1) {
#pragma unroll
        for (int o = 0; o < 10; ++o) t[o] += __shfl_xor(t[o], m);
    }
    if (l == 0) {
        float as = 0.f, ad = 0.f;
#pragma unroll
        for (int o = 0; o < 10; ++o) {
            h2lin[(size_t)wid * 16 + o] = t[o];
            as += t[o] * as2v[o];
            ad += t[o] * ad2v[o];
        }
        als2[wid] = as;
        ald2[wid] = ad;
    }
}

// ---------------- gather layer 2 (predicated 4-wide, srcs-only) + pool ----
__global__ void k_g2pool(const int* __restrict__ indptr, const int* __restrict__ srcs,
                         const float* __restrict__ als2, const float* __restrict__ ald2,
                         const float* __restrict__ h2lin, const float* __restrict__ b2,
                         const int* __restrict__ batch, float* __restrict__ pooled) {
    int wave = (blockIdx.x * 256 + threadIdx.x) >> 6;
    int lane = threadIdx.x & 63;
    int grp = lane >> 4, c = lane & 15;
    int node = wave * 4 + grp;
    float acc = 0.f;
    int g = -1;
    if (node < NN) {
        int p0 = indptr[node], p1 = indptr[node + 1];
        int last = p1 - 1;
        float ad2n = ald2[node];
        float dsum = 0.f;
        for (int p = p0; p < p1; p += 4) {
            int i1 = p + 1, i2 = p + 2, i3 = p + 3;
            unsigned s0 = (unsigned)srcs[p];
            unsigned s1 = (unsigned)srcs[i1 < p1 ? i1 : last];
            unsigned s2 = (unsigned)srcs[i2 < p1 ? i2 : last];
            unsigned s3 = (unsigned)srcs[i3 < p1 ? i3 : last];
            float v0 = als2[s0] + ad2n;
            float v1 = als2[s1] + ad2n;
            float v2 = als2[s2] + ad2n;
            float v3 = als2[s3] + ad2n;
            float h0 = 0.f, h1_ = 0.f, h2 = 0.f, h3 = 0.f;
            if (c < 10) {
                h0 = h2lin[(s0 << 4) + (unsigned)c];
                h1_ = h2lin[(s1 << 4) + (unsigned)c];
                h2 = h2lin[(s2 << 4) + (unsigned)c];
                h3 = h2lin[(s3 << 4) + (unsigned)c];
            }
            v0 = v0 > 0.f ? v0 : 0.2f * v0;
            v1 = v1 > 0.f ? v1 : 0.2f * v1;
            v2 = v2 > 0.f ? v2 : 0.2f * v2;
            v3 = v3 > 0.f ? v3 : 0.2f * v3;
            float w0 = __expf(v0);
            float w1 = (i1 < p1) ? __expf(v1) : 0.f;
            float w2 = (i2 < p1) ? __expf(v2) : 0.f;
            float w3 = (i3 < p1) ? __expf(v3) : 0.f;
            dsum += (w0 + w1) + (w2 + w3);
            acc += w0 * h0 + w1 * h1_ + w2 * h2 + w3 * h3;
        }
        if (c < 10) acc = acc / dsum + b2[c];
        else acc = 0.f;
        g = batch[node];
    }
    int g0 = __shfl(g, 0);
    bool uni = __all((node >= NN) || (g == g0));
    if (uni) {
        if (g0 >= 0) {
            acc += __shfl_xor(acc, 16);
            acc += __shfl_xor(acc, 32);
            if (grp == 0 && c < 10)
                atomicAdd(pooled + g0 * 10 + c, acc);
        }
    } else if (node < NN && c < 10) {
        atomicAdd(pooled + g * 10 + c, acc);
    }
}

// ---------------- mean + log_softmax --------------------------------------
__global__ void k_final(const float* __restrict__ pooled, const int* __restrict__ gcount,
                        float* __restrict__ out) {
    int g = threadIdx.x;
    if (g >= NG) return;
    float c = fmaxf((float)gcount[g], 1.0f);
    float m[10];
    float mx = -1e30f;
#pragma unroll
    for (int i = 0; i < 10; ++i) {
        m[i] = pooled[g * 10 + i] / c;
        mx = fmaxf(mx, m[i]);
    }
    float s = 0.f;
#pragma unroll
    for (int i = 0; i < 10; ++i) s += expf(m[i] - mx);
    float lse = mx + logf(s);
#pragma unroll
    for (int i = 0; i < 10; ++i) out[g * 10 + i] = m[i] - lse;
}

extern "C" void kernel_launch(void* const* d_in, const int* in_sizes, int n_in,
                              void* d_out, int out_size, void* d_ws, size_t ws_size,
                              hipStream_t stream) {
    const float* x   = (const float*)d_in[0];
    const int*   ei  = (const int*)d_in[1];
    const int*   bat = (const int*)d_in[3];
    const float* W1  = (const float*)d_in[4];
    const float* as1 = (const float*)d_in[5];
    const float* ad1 = (const float*)d_in[6];
    const float* b1  = (const float*)d_in[7];
    const float* W2  = (const float*)d_in[8];
    const float* as2 = (const float*)d_in[9];
    const float* ad2 = (const float*)d_in[10];
    const float* b2  = (const float*)d_in[11];
    float* out = (float*)d_out;

    char* ws = (char*)d_ws;
    size_t off = 0;
    auto alloc = [&](size_t bytes) -> size_t {
        size_t o = off;
        off = (off + bytes + 255) & ~(size_t)255;
        return o;
    };
    size_t o_counts = alloc((size_t)NN * 4);
    size_t o_pooled = alloc((size_t)NG * 10 * 4);
    size_t o_gcount = alloc((size_t)NG * 4);
    size_t zero_bytes = off;
    size_t o_ord    = alloc((size_t)ETOT * 4);
    size_t o_indptr = alloc((size_t)(NN + 1) * 4);
    size_t o_edges  = alloc((size_t)ETOT * 16);
    size_t o_srcs   = alloc((size_t)ETOT * 4);
    size_t o_h1f8   = alloc((size_t)NN * 256);
    size_t o_als1   = alloc((size_t)NN * 4 * 4);
    size_t o_ald1   = alloc((size_t)NN * 4 * 4);
    size_t o_h2lin  = alloc((size_t)NN * 16 * 4);
    size_t o_als2   = alloc((size_t)NN * 4);
    size_t o_ald2   = alloc((size_t)NN * 4);
    size_t o_wb     = alloc((size_t)256 * 128 * 2);
    size_t o_xb     = alloc((size_t)NN * 128 * 2);
    (void)ws_size;

    int*   counts = (int*)(ws + o_counts);
    float* pooled = (float*)(ws + o_pooled);
    int*   gcount = (int*)(ws + o_gcount);
    int*   ord    = (int*)(ws + o_ord);
    int*   indptr = (int*)(ws + o_indptr);
    uint4* edges  = (uint4*)(ws + o_edges);
    int*   srcs   = (int*)(ws + o_srcs);
    unsigned char*  h1f8 = (unsigned char*)(ws + o_h1f8);
    float* als1   = (float*)(ws + o_als1);
    float* ald1   = (float*)(ws + o_ald1);
    float* h2lin  = (float*)(ws + o_h2lin);
    float* als2   = (float*)(ws + o_als2);
    float* ald2   = (float*)(ws + o_ald2);
    unsigned short* wb = (unsigned short*)(ws + o_wb);
    unsigned short* xb = (unsigned short*)(ws + o_xb);

    int n16 = (int)(zero_bytes / 16);
    int zB = (n16 + 255) / 256;
    int xB = (NN * 128 / 8 + 255) / 256;   // 3125
    int gE = (ETOT + 255) / 256;           // 2149
    int gW = (NN + 3) / 4;                 // 12500
    int gemmB = (NN + 31) / 32;            // 1563

    k_prep<<<zB + 128 + xB, 256, 0, stream>>>((uint4*)ws, n16, zB, W1, wb, x, xb);
    k_big<<<gE + gemmB, 256, 0, stream>>>(gemmB, gE, ei, bat, counts, ord, gcount,
                                          xb, wb, as1, ad1, h1f8, als1, ald1);
    k_scan<<<1, 1024, 0, stream>>>(counts, indptr);
    k_fill<<<gE, 256, 0, stream>>>(ei, indptr, ord, als1, ald1, edges, srcs);
    k_gather1<<<gW, 256, 0, stream>>>(indptr, edges, h1f8, b1, W2, as2, ad2,
                                      h2lin, als2, ald2);
    k_g2pool<<<gW, 256, 0, stream>>>(indptr, srcs, als2, ald2, h2lin, b2, bat, pooled);
    k_final<<<1, 64, 0, stream>>>(pooled, gcount, out);
    (void)n_in; (void)in_sizes; (void)out_size;
}